// Round 6
// baseline (685.956 us; speedup 1.0000x reference)
//
#include <hip/hip_runtime.h>
#include <hip/hip_fp16.h>

#define IN_CH 128
#define HEADS 4
#define OUT_CH 32
#define HC 128           // HEADS*OUT_CH
#define CHUNK 2048       // scan chunk (256 thr x 8)

__device__ __forceinline__ unsigned flip_f32(float x) {
  unsigned u = __float_as_uint(x);
  return (u & 0x80000000u) ? ~u : (u | 0x80000000u);
}
__device__ __forceinline__ float unflip_f32(unsigned k) {
  unsigned u = (k & 0x80000000u) ? (k ^ 0x80000000u) : ~k;
  return __uint_as_float(u);
}
__device__ __forceinline__ float fast_tanh(float x) {
  return 1.f - 2.f / (__expf(2.f * x) + 1.f);
}

// projh[N][128] (fp16) = x[N][128] @ W[128][128]
__global__ __launch_bounds__(256) void gemm_xW_h(const float* __restrict__ x,
                                                 const float* __restrict__ W,
                                                 __half* __restrict__ projh, int N) {
  __shared__ float xs[128][132];
  __shared__ float ws[128][128];
  const int tid = threadIdx.x;
  const int row0 = blockIdx.x * 128;

  {
    const float4* Wv = (const float4*)W;
    float4* wsv = (float4*)ws;
#pragma unroll
    for (int i = 0; i < 16; ++i) wsv[i * 256 + tid] = Wv[i * 256 + tid];
  }
  {
    const int r = tid >> 1;
    const int k0 = (tid & 1) * 64;
    const int grow = row0 + r;
    const bool valid = grow < N;
    const float4* src = (const float4*)(x + (size_t)grow * IN_CH + k0);
#pragma unroll
    for (int i = 0; i < 16; ++i) {
      float4 v = valid ? src[i] : make_float4(0.f, 0.f, 0.f, 0.f);
      const int k = k0 + i * 4;
      xs[k][r] = v.x; xs[k + 1][r] = v.y; xs[k + 2][r] = v.z; xs[k + 3][r] = v.w;
    }
  }
  __syncthreads();

  const int cg = tid & 15;
  const int rg = tid >> 4;
  float acc[8][8];
#pragma unroll
  for (int r = 0; r < 8; ++r)
#pragma unroll
    for (int c = 0; c < 8; ++c) acc[r][c] = 0.f;

#pragma unroll 4
  for (int k = 0; k < 128; ++k) {
    float4 a0 = *(const float4*)&xs[k][rg * 8];
    float4 a1 = *(const float4*)&xs[k][rg * 8 + 4];
    float4 b0 = *(const float4*)&ws[k][cg * 8];
    float4 b1 = *(const float4*)&ws[k][cg * 8 + 4];
    float xv[8] = {a0.x, a0.y, a0.z, a0.w, a1.x, a1.y, a1.z, a1.w};
    float wv[8] = {b0.x, b0.y, b0.z, b0.w, b1.x, b1.y, b1.z, b1.w};
#pragma unroll
    for (int r = 0; r < 8; ++r)
#pragma unroll
      for (int c = 0; c < 8; ++c) acc[r][c] += xv[r] * wv[c];
  }

#pragma unroll
  for (int r = 0; r < 8; ++r) {
    const int grow = row0 + rg * 8 + r;
    if (grow < N) {
      __half2 hh[4];
#pragma unroll
      for (int c = 0; c < 4; ++c) hh[c] = __floats2half2_rn(acc[r][2 * c], acc[r][2 * c + 1]);
      *(float4*)(projh + (size_t)grow * HC + cg * 8) = *(float4*)hh;
    }
  }
}

// histogram over exact destination node
__global__ __launch_bounds__(256) void edge_hist(const int* __restrict__ ecol,
                                                 int* __restrict__ hist, int E) {
  const int i = blockIdx.x * 256 + threadIdx.x;
  if (i < E) atomicAdd(&hist[ecol[i]], 1);
}

// --- hierarchical exclusive scan ---
__device__ __forceinline__ int block_scan_excl(int tsum, int* ls, int tid, int* total) {
  ls[tid] = tsum;
  __syncthreads();
  for (int off = 1; off < 256; off <<= 1) {
    int v = (tid >= off) ? ls[tid - off] : 0;
    __syncthreads();
    ls[tid] += v;
    __syncthreads();
  }
  *total = ls[255];
  return ls[tid] - tsum;
}

__global__ __launch_bounds__(256) void k_scan_a(const int* __restrict__ hist,
                                                int* __restrict__ sums, int nb) {
  __shared__ int ls[256];
  const int tid = threadIdx.x;
  const int base = blockIdx.x * CHUNK + tid * 8;
  int t = 0;
#pragma unroll
  for (int j = 0; j < 8; ++j) { const int i = base + j; if (i < nb) t += hist[i]; }
  int total;
  block_scan_excl(t, ls, tid, &total);
  if (tid == 0) sums[blockIdx.x] = total;
}

__global__ __launch_bounds__(256) void k_scan_b(int* __restrict__ sums, int nc,
                                                int* __restrict__ starts,
                                                int* __restrict__ cursor, int nb) {
  __shared__ int ls[256];
  const int tid = threadIdx.x;
  const int t = (tid < nc) ? sums[tid] : 0;
  int total;
  const int excl = block_scan_excl(t, ls, tid, &total);
  if (tid < nc) sums[tid] = excl;
  if (tid == 0) { starts[nb] = total; cursor[nb] = total; }
}

__global__ __launch_bounds__(256) void k_scan_c(const int* __restrict__ hist,
                                                const int* __restrict__ sums,
                                                int* __restrict__ starts,
                                                int* __restrict__ cursor, int nb) {
  __shared__ int ls[256];
  const int tid = threadIdx.x;
  const int base = blockIdx.x * CHUNK + tid * 8;
  int t = 0;
#pragma unroll
  for (int j = 0; j < 8; ++j) { const int i = base + j; if (i < nb) t += hist[i]; }
  int total;
  const int excl = block_scan_excl(t, ls, tid, &total);
  int run = sums[blockIdx.x] + excl;
#pragma unroll
  for (int j = 0; j < 8; ++j) {
    const int i = base + j;
    if (i < nb) { starts[i] = run; cursor[i] = run; run += hist[i]; }
  }
}

// CSR build: rows[p] = src row, sorted by destination
__global__ __launch_bounds__(256) void scatter_rows(const int* __restrict__ erow,
                                                    const int* __restrict__ ecol,
                                                    int* __restrict__ cursor,
                                                    int* __restrict__ rows, int E) {
  const int i = blockIdx.x * 256 + threadIdx.x;
  if (i >= E) return;
  const int p = atomicAdd(&cursor[ecol[i]], 1);
  rows[p] = erow[i];
}

// Fused single-gather pass: wave per node, online softmax with node-local max.
// Lane l holds channels 2l, 2l+1 (head = l>>4). One __half2 gather per edge.
// out <- unnormalized num (fp32); den/L per (node,head); global head max via atomics.
__global__ __launch_bounds__(256) void fused_apply(const __half* __restrict__ projh,
                                                   const int* __restrict__ rows,
                                                   const int* __restrict__ starts,
                                                   const float* __restrict__ att,
                                                   float* __restrict__ out,
                                                   float* __restrict__ den_arr,
                                                   float* __restrict__ L_arr,
                                                   unsigned* __restrict__ headmax_key, int N) {
  __shared__ unsigned blkmax[HEADS];
  const int tid = threadIdx.x;
  if (tid < HEADS) blkmax[tid] = 0u;
  __syncthreads();
  const int lane = tid & 63;
  const int n = blockIdx.x * 4 + (tid >> 6);
  const float a0 = (n < N) ? att[2 * lane] : 0.f;
  const float a1 = (n < N) ? att[2 * lane + 1] : 0.f;

  if (n < N) {
    // dst row: loaded once
    const float2 dv = __half22float2(((const __half2*)(projh + (size_t)n * HC))[lane]);
    const int beg = starts[n];
    const int end = starts[n + 1];

    float num0 = 0.f, num1 = 0.f, den = 0.f, mrun = -3.0e38f;
    int i = beg;
    for (; i + 4 <= end; i += 4) {
      int r4[4];
#pragma unroll
      for (int u = 0; u < 4; ++u) r4[u] = rows[i + u];
      __half2 hv[4];
#pragma unroll
      for (int u = 0; u < 4; ++u)
        hv[u] = ((const __half2*)(projh + (size_t)r4[u] * HC))[lane];
#pragma unroll
      for (int u = 0; u < 4; ++u) {
        const float2 sv = __half22float2(hv[u]);
        float p = fast_tanh(sv.x + dv.x) * a0 + fast_tanh(sv.y + dv.y) * a1;
#pragma unroll
        for (int m = 8; m >= 1; m >>= 1) p += __shfl_xor(p, m, 64);  // 16-lane head group
        const float mn = fmaxf(mrun, p);
        const float rs = __expf(mrun - mn);
        const float w = __expf(p - mn);
        num0 = num0 * rs + sv.x * w;
        num1 = num1 * rs + sv.y * w;
        den = den * rs + w;
        mrun = mn;
      }
    }
    for (; i < end; ++i) {
      const int row = rows[i];
      const float2 sv = __half22float2(((const __half2*)(projh + (size_t)row * HC))[lane]);
      float p = fast_tanh(sv.x + dv.x) * a0 + fast_tanh(sv.y + dv.y) * a1;
#pragma unroll
      for (int m = 8; m >= 1; m >>= 1) p += __shfl_xor(p, m, 64);
      const float mn = fmaxf(mrun, p);
      const float rs = __expf(mrun - mn);
      const float w = __expf(p - mn);
      num0 = num0 * rs + sv.x * w;
      num1 = num1 * rs + sv.y * w;
      den = den * rs + w;
      mrun = mn;
    }

    ((float2*)out)[(size_t)n * 64 + lane] = make_float2(num0, num1);
    if ((lane & 15) == 0) {
      const int h = lane >> 4;
      den_arr[(size_t)n * HEADS + h] = den;
      L_arr[(size_t)n * HEADS + h] = mrun;
      atomicMax(&blkmax[h], flip_f32(mrun));
    }
  }
  __syncthreads();
  if (tid < HEADS) atomicMax(&headmax_key[tid], blkmax[tid]);
}

// out = num * scale / max(den * scale, 1e-12), scale = exp(L_n - M)  [exact ref clamp]
__global__ __launch_bounds__(256) void finalize(float* __restrict__ out,
                                                const float* __restrict__ den_arr,
                                                const float* __restrict__ L_arr,
                                                const unsigned* __restrict__ headmax_key,
                                                int N) {
  const int idx = blockIdx.x * 256 + threadIdx.x;  // float4 index
  const int total = N * 32;
  if (idx >= total) return;
  const int node = idx >> 5;
  const int h = (idx >> 3) & 3;
  const float M = unflip_f32(headmax_key[h]);
  const float L = L_arr[(size_t)node * HEADS + h];
  const float den = den_arr[(size_t)node * HEADS + h];
  const float scale = __expf(L - M);
  const float inv = scale / fmaxf(den * scale, 1e-12f);
  float4 v = ((float4*)out)[idx];
  v.x *= inv; v.y *= inv; v.z *= inv; v.w *= inv;
  ((float4*)out)[idx] = v;
}

extern "C" void kernel_launch(void* const* d_in, const int* in_sizes, int n_in,
                              void* d_out, int out_size, void* d_ws, size_t ws_size,
                              hipStream_t stream) {
  const float* x    = (const float*)d_in[0];
  const int*   eidx = (const int*)d_in[1];  // [2][E]: row(src) then col(dst)
  const float* W    = (const float*)d_in[2];
  const float* att  = (const float*)d_in[3];
  float* out = (float*)d_out;

  const int N = in_sizes[0] / IN_CH;
  const int E = in_sizes[1] / 2;
  const int nc = (N + CHUNK - 1) / CHUNK;  // scan chunks (<= 256)

  // ws layout (aligned pieces)
  char* p = (char*)d_ws;
  __half* projh = (__half*)p;        p += (size_t)N * HC * 2;
  int* rows = (int*)p;               p += (size_t)E * 4;
  int* hist = (int*)p;               p += (size_t)N * 4;
  int* starts = (int*)p;             p += (size_t)(N + 1) * 4;
  int* cursor = (int*)p;             p += (size_t)(N + 1) * 4;
  int* sums = (int*)p;               p += 1024;
  float* den_arr = (float*)p;        p += (size_t)N * HEADS * 4;
  float* L_arr = (float*)p;          p += (size_t)N * HEADS * 4;
  p = (char*)(((size_t)p + 15) & ~(size_t)15);
  unsigned* headmax = (unsigned*)p;  p += 16;

  hipMemsetAsync(hist, 0, (size_t)N * sizeof(int), stream);
  hipMemsetAsync(headmax, 0, 4 * sizeof(unsigned), stream);

  gemm_xW_h<<<(N + 127) / 128, 256, 0, stream>>>(x, W, projh, N);
  edge_hist<<<(E + 255) / 256, 256, 0, stream>>>(eidx + E, hist, E);
  k_scan_a<<<nc, 256, 0, stream>>>(hist, sums, N);
  k_scan_b<<<1, 256, 0, stream>>>(sums, nc, starts, cursor, N);
  k_scan_c<<<nc, 256, 0, stream>>>(hist, sums, starts, cursor, N);
  scatter_rows<<<(E + 255) / 256, 256, 0, stream>>>(eidx, eidx + E, cursor, rows, E);
  fused_apply<<<(N + 3) / 4, 256, 0, stream>>>(projh, rows, starts, att, out,
                                               den_arr, L_arr, headmax, N);
  finalize<<<(N * 32 + 255) / 256, 256, 0, stream>>>(out, den_arr, L_arr, headmax, N);
}

// Round 7
// 678.597 us; speedup vs baseline: 1.0108x; 1.0108x over previous
//
#include <hip/hip_runtime.h>
#include <hip/hip_fp16.h>

#define IN_CH 128
#define HEADS 4
#define OUT_CH 32
#define HC 128           // HEADS*OUT_CH
#define CHUNK 2048       // scan chunk (256 thr x 8)

__device__ __forceinline__ unsigned flip_f32(float x) {
  unsigned u = __float_as_uint(x);
  return (u & 0x80000000u) ? ~u : (u | 0x80000000u);
}
__device__ __forceinline__ float unflip_f32(unsigned k) {
  unsigned u = (k & 0x80000000u) ? (k ^ 0x80000000u) : ~k;
  return __uint_as_float(u);
}

// projh[N][128] (fp16) = x[N][128] @ W[128][128]
__global__ __launch_bounds__(256) void gemm_xW_h(const float* __restrict__ x,
                                                 const float* __restrict__ W,
                                                 __half* __restrict__ projh, int N) {
  __shared__ float xs[128][132];
  __shared__ float ws[128][128];
  const int tid = threadIdx.x;
  const int row0 = blockIdx.x * 128;

  {
    const float4* Wv = (const float4*)W;
    float4* wsv = (float4*)ws;
#pragma unroll
    for (int i = 0; i < 16; ++i) wsv[i * 256 + tid] = Wv[i * 256 + tid];
  }
  {
    const int r = tid >> 1;
    const int k0 = (tid & 1) * 64;
    const int grow = row0 + r;
    const bool valid = grow < N;
    const float4* src = (const float4*)(x + (size_t)grow * IN_CH + k0);
#pragma unroll
    for (int i = 0; i < 16; ++i) {
      float4 v = valid ? src[i] : make_float4(0.f, 0.f, 0.f, 0.f);
      const int k = k0 + i * 4;
      xs[k][r] = v.x; xs[k + 1][r] = v.y; xs[k + 2][r] = v.z; xs[k + 3][r] = v.w;
    }
  }
  __syncthreads();

  const int cg = tid & 15;
  const int rg = tid >> 4;
  float acc[8][8];
#pragma unroll
  for (int r = 0; r < 8; ++r)
#pragma unroll
    for (int c = 0; c < 8; ++c) acc[r][c] = 0.f;

#pragma unroll 4
  for (int k = 0; k < 128; ++k) {
    float4 a0 = *(const float4*)&xs[k][rg * 8];
    float4 a1 = *(const float4*)&xs[k][rg * 8 + 4];
    float4 b0 = *(const float4*)&ws[k][cg * 8];
    float4 b1 = *(const float4*)&ws[k][cg * 8 + 4];
    float xv[8] = {a0.x, a0.y, a0.z, a0.w, a1.x, a1.y, a1.z, a1.w};
    float wv[8] = {b0.x, b0.y, b0.z, b0.w, b1.x, b1.y, b1.z, b1.w};
#pragma unroll
    for (int r = 0; r < 8; ++r)
#pragma unroll
      for (int c = 0; c < 8; ++c) acc[r][c] += xv[r] * wv[c];
  }

#pragma unroll
  for (int r = 0; r < 8; ++r) {
    const int grow = row0 + rg * 8 + r;
    if (grow < N) {
      __half2 hh[4];
#pragma unroll
      for (int c = 0; c < 4; ++c) hh[c] = __floats2half2_rn(acc[r][2 * c], acc[r][2 * c + 1]);
      *(float4*)(projh + (size_t)grow * HC + cg * 8) = *(float4*)hh;
    }
  }
}

// histogram over exact destination node
__global__ __launch_bounds__(256) void edge_hist(const int* __restrict__ ecol,
                                                 int* __restrict__ hist, int E) {
  const int i = blockIdx.x * 256 + threadIdx.x;
  if (i < E) atomicAdd(&hist[ecol[i]], 1);
}

// --- hierarchical exclusive scan ---
__device__ __forceinline__ int block_scan_excl(int tsum, int* ls, int tid, int* total) {
  ls[tid] = tsum;
  __syncthreads();
  for (int off = 1; off < 256; off <<= 1) {
    int v = (tid >= off) ? ls[tid - off] : 0;
    __syncthreads();
    ls[tid] += v;
    __syncthreads();
  }
  *total = ls[255];
  return ls[tid] - tsum;
}

__global__ __launch_bounds__(256) void k_scan_a(const int* __restrict__ hist,
                                                int* __restrict__ sums, int nb) {
  __shared__ int ls[256];
  const int tid = threadIdx.x;
  const int base = blockIdx.x * CHUNK + tid * 8;
  int t = 0;
#pragma unroll
  for (int j = 0; j < 8; ++j) { const int i = base + j; if (i < nb) t += hist[i]; }
  int total;
  block_scan_excl(t, ls, tid, &total);
  if (tid == 0) sums[blockIdx.x] = total;
}

__global__ __launch_bounds__(256) void k_scan_b(int* __restrict__ sums, int nc,
                                                int* __restrict__ starts,
                                                int* __restrict__ cursor, int nb) {
  __shared__ int ls[256];
  const int tid = threadIdx.x;
  const int t = (tid < nc) ? sums[tid] : 0;
  int total;
  const int excl = block_scan_excl(t, ls, tid, &total);
  if (tid < nc) sums[tid] = excl;
  if (tid == 0) { starts[nb] = total; cursor[nb] = total; }
}

__global__ __launch_bounds__(256) void k_scan_c(const int* __restrict__ hist,
                                                const int* __restrict__ sums,
                                                int* __restrict__ starts,
                                                int* __restrict__ cursor, int nb) {
  __shared__ int ls[256];
  const int tid = threadIdx.x;
  const int base = blockIdx.x * CHUNK + tid * 8;
  int t = 0;
#pragma unroll
  for (int j = 0; j < 8; ++j) { const int i = base + j; if (i < nb) t += hist[i]; }
  int total;
  const int excl = block_scan_excl(t, ls, tid, &total);
  int run = sums[blockIdx.x] + excl;
#pragma unroll
  for (int j = 0; j < 8; ++j) {
    const int i = base + j;
    if (i < nb) { starts[i] = run; cursor[i] = run; run += hist[i]; }
  }
}

// CSR build: rows[p] = src row, sorted by destination
__global__ __launch_bounds__(256) void scatter_rows(const int* __restrict__ erow,
                                                    const int* __restrict__ ecol,
                                                    int* __restrict__ cursor,
                                                    int* __restrict__ rows, int E) {
  const int i = blockIdx.x * 256 + threadIdx.x;
  if (i >= E) return;
  const int p = atomicAdd(&cursor[ecol[i]], 1);
  rows[p] = erow[i];
}

// Wave per node, 4 edges in parallel via 16-lane slots.
// lane = slot*16 + sl; lane handles channels sl*8..sl*8+7 (one dwordx4 = 4x half2);
// head = sl>>2 (4 lanes/head -> 2-step reduce). Unshifted w=exp(p) (p bounded ~35,
// no overflow); ref clamp domain restored in finalize via e^{-M}.
__global__ __launch_bounds__(256) void fused_apply_v2(const __half* __restrict__ projh,
                                                      const int* __restrict__ rows,
                                                      const int* __restrict__ starts,
                                                      const float* __restrict__ att,
                                                      float* __restrict__ out,
                                                      float* __restrict__ den_arr,
                                                      unsigned* __restrict__ headmax_key,
                                                      int N) {
  __shared__ unsigned blkmax[HEADS];
  const int tid = threadIdx.x;
  if (tid < HEADS) blkmax[tid] = 0u;
  __syncthreads();
  const int lane = tid & 63;
  const int sl = lane & 15;
  const int slot = lane >> 4;
  const int n = blockIdx.x * 4 + (tid >> 6);

  float num[8] = {0.f, 0.f, 0.f, 0.f, 0.f, 0.f, 0.f, 0.f};
  float den = 0.f;
  float lmax = -3.0e38f;

  if (n < N) {
    // att for this lane's 8 channels; fold tanh: p = sum(av) + sum(-2*av*rcp(e^{2x}+1))
    float av[8], av2[8];
    float av_sum = 0.f;
#pragma unroll
    for (int c = 0; c < 8; ++c) {
      av[c] = att[sl * 8 + c];
      av2[c] = -2.f * av[c];
      av_sum += av[c];
    }
    (void)av;
    // dst row channels (loaded once)
    float dv[8];
    {
      const float4 draw = *(const float4*)(projh + (size_t)n * HC + sl * 8);
      const __half2* dh = (const __half2*)&draw;
#pragma unroll
      for (int c = 0; c < 4; ++c) {
        const float2 f = __half22float2(dh[c]);
        dv[2 * c] = f.x; dv[2 * c + 1] = f.y;
      }
    }
    const int beg = starts[n];
    const int end = starts[n + 1];
    const float K = 2.f * 1.4426950408889634f;  // exp2 scale for e^{2x}

    int i = beg + slot;
    // 2x unroll: two gathers in flight per lane
    for (; i + 4 < end; i += 8) {
      const int r0 = rows[i];
      const int r1 = rows[i + 4];
      const float4 g0 = *(const float4*)(projh + (size_t)r0 * HC + sl * 8);
      const float4 g1 = *(const float4*)(projh + (size_t)r1 * HC + sl * 8);
#pragma unroll
      for (int q = 0; q < 2; ++q) {
        const float4 graw = q ? g1 : g0;
        const __half2* gh = (const __half2*)&graw;
        float sv[8];
#pragma unroll
        for (int c = 0; c < 4; ++c) {
          const float2 f = __half22float2(gh[c]);
          sv[2 * c] = f.x; sv[2 * c + 1] = f.y;
        }
        float p = av_sum;
#pragma unroll
        for (int c = 0; c < 8; ++c) {
          const float e = __builtin_amdgcn_exp2f(K * (sv[c] + dv[c]));
          p += av2[c] * __builtin_amdgcn_rcpf(e + 1.f);
        }
        p += __shfl_xor(p, 1, 64);
        p += __shfl_xor(p, 2, 64);
        const float w = __expf(p);
        lmax = fmaxf(lmax, p);
        den += w;
#pragma unroll
        for (int c = 0; c < 8; ++c) num[c] += sv[c] * w;
      }
    }
    for (; i < end; i += 4) {
      const int r0 = rows[i];
      const float4 graw = *(const float4*)(projh + (size_t)r0 * HC + sl * 8);
      const __half2* gh = (const __half2*)&graw;
      float sv[8];
#pragma unroll
      for (int c = 0; c < 4; ++c) {
        const float2 f = __half22float2(gh[c]);
        sv[2 * c] = f.x; sv[2 * c + 1] = f.y;
      }
      float p = av_sum;
#pragma unroll
      for (int c = 0; c < 8; ++c) {
        const float e = __builtin_amdgcn_exp2f(K * (sv[c] + dv[c]));
        p += av2[c] * __builtin_amdgcn_rcpf(e + 1.f);
      }
      p += __shfl_xor(p, 1, 64);
      p += __shfl_xor(p, 2, 64);
      const float w = __expf(p);
      lmax = fmaxf(lmax, p);
      den += w;
#pragma unroll
      for (int c = 0; c < 8; ++c) num[c] += sv[c] * w;
    }

    // combine the 4 slots (toggle slot bits: lane xor 16, 32)
#pragma unroll
    for (int m = 16; m <= 32; m <<= 1) {
#pragma unroll
      for (int c = 0; c < 8; ++c) num[c] += __shfl_xor(num[c], m, 64);
      den += __shfl_xor(den, m, 64);
      lmax = fmaxf(lmax, __shfl_xor(lmax, m, 64));
    }

    if (slot == 0) {
      float4 o0 = make_float4(num[0], num[1], num[2], num[3]);
      float4 o1 = make_float4(num[4], num[5], num[6], num[7]);
      float4* dst = (float4*)(out + (size_t)n * HC + sl * 8);
      dst[0] = o0; dst[1] = o1;
      if ((sl & 3) == 0) {
        const int h = sl >> 2;
        den_arr[(size_t)n * HEADS + h] = den;
        atomicMax(&blkmax[h], flip_f32(lmax));
      }
    }
  }
  __syncthreads();
  if (tid < HEADS) atomicMax(&headmax_key[tid], blkmax[tid]);
}

// out = num * e^{-M} / max(den * e^{-M}, 1e-12)   [exact reference clamp domain]
__global__ __launch_bounds__(256) void finalize(float* __restrict__ out,
                                                const float* __restrict__ den_arr,
                                                const unsigned* __restrict__ headmax_key,
                                                int N) {
  const int idx = blockIdx.x * 256 + threadIdx.x;  // float4 index
  const int total = N * 32;
  if (idx >= total) return;
  const int node = idx >> 5;
  const int h = (idx >> 3) & 3;
  const float M = unflip_f32(headmax_key[h]);
  const float scale = __expf(-M);
  const float den = den_arr[(size_t)node * HEADS + h];
  const float inv = scale / fmaxf(den * scale, 1e-12f);
  float4 v = ((float4*)out)[idx];
  v.x *= inv; v.y *= inv; v.z *= inv; v.w *= inv;
  ((float4*)out)[idx] = v;
}

extern "C" void kernel_launch(void* const* d_in, const int* in_sizes, int n_in,
                              void* d_out, int out_size, void* d_ws, size_t ws_size,
                              hipStream_t stream) {
  const float* x    = (const float*)d_in[0];
  const int*   eidx = (const int*)d_in[1];  // [2][E]: row(src) then col(dst)
  const float* W    = (const float*)d_in[2];
  const float* att  = (const float*)d_in[3];
  float* out = (float*)d_out;

  const int N = in_sizes[0] / IN_CH;
  const int E = in_sizes[1] / 2;
  const int nc = (N + CHUNK - 1) / CHUNK;  // scan chunks (<= 256)

  // ws layout (aligned pieces)
  char* p = (char*)d_ws;
  __half* projh = (__half*)p;        p += (size_t)N * HC * 2;
  int* rows = (int*)p;               p += (size_t)E * 4;
  int* hist = (int*)p;               p += (size_t)N * 4;
  int* starts = (int*)p;             p += (size_t)(N + 1) * 4;
  int* cursor = (int*)p;             p += (size_t)(N + 1) * 4;
  int* sums = (int*)p;               p += 1024;
  float* den_arr = (float*)p;        p += (size_t)N * HEADS * 4;
  p = (char*)(((size_t)p + 15) & ~(size_t)15);
  unsigned* headmax = (unsigned*)p;  p += 16;

  hipMemsetAsync(hist, 0, (size_t)N * sizeof(int), stream);
  hipMemsetAsync(headmax, 0, 4 * sizeof(unsigned), stream);

  gemm_xW_h<<<(N + 127) / 128, 256, 0, stream>>>(x, W, projh, N);
  edge_hist<<<(E + 255) / 256, 256, 0, stream>>>(eidx + E, hist, E);
  k_scan_a<<<nc, 256, 0, stream>>>(hist, sums, N);
  k_scan_b<<<1, 256, 0, stream>>>(sums, nc, starts, cursor, N);
  k_scan_c<<<nc, 256, 0, stream>>>(hist, sums, starts, cursor, N);
  scatter_rows<<<(E + 255) / 256, 256, 0, stream>>>(eidx, eidx + E, cursor, rows, E);
  fused_apply_v2<<<(N + 3) / 4, 256, 0, stream>>>(projh, rows, starts, att, out,
                                                  den_arr, headmax, N);
  finalize<<<(N * 32 + 255) / 256, 256, 0, stream>>>(out, den_arr, headmax, N);
}